// Round 9
// baseline (203.089 us; speedup 1.0000x reference)
//
#include <hip/hip_runtime.h>
#include <hip/hip_bf16.h>
#include <math.h>

#define B_  2
#define T_  2048
#define D_  1024
#define H_  16
#define HD_ 64

typedef __attribute__((ext_vector_type(8))) short short8;
typedef __attribute__((ext_vector_type(4))) float f32x4;
typedef __attribute__((ext_vector_type(4))) unsigned uint32x4;

#if __has_builtin(__builtin_amdgcn_exp2f)
#define EXP2F __builtin_amdgcn_exp2f
#else
#define EXP2F exp2f
#endif

__device__ __forceinline__ ushort f2bf(float x) {
    unsigned u = __builtin_bit_cast(unsigned, x);
    return (ushort)((u + 0x7FFFu + ((u >> 16) & 1u)) >> 16);  // RTNE
}

// round-half-up bf16 pair pack
__device__ __forceinline__ unsigned pack_bf2_fast(float a, float b) {
    unsigned ua = __builtin_bit_cast(unsigned, a) + 0x8000u;
    unsigned ub = __builtin_bit_cast(unsigned, b) + 0x8000u;
    return (ua >> 16) | (ub & 0xFFFF0000u);
}

__device__ __forceinline__ void load_lds_16B(const ushort* g, ushort* l) {
    __builtin_amdgcn_global_load_lds(
        (const __attribute__((address_space(1))) unsigned*)g,
        (__attribute__((address_space(3))) unsigned*)l, 16, 0, 0);
}

// ---------------------------------------------------------------------------
// Merged prep: [0,512) cast x->bf16; [512,1280) transpose Wqkv; [1280,1536)
// transpose Wout. Wt stores are 16B/lane (full-line coalesced).
// ---------------------------------------------------------------------------
__global__ __launch_bounds__(256)
void prep_kernel(const float* __restrict__ x, ushort* __restrict__ xb,
                 const float* __restrict__ Wqkv, ushort* __restrict__ Wqkvt,
                 const float* __restrict__ Wout, ushort* __restrict__ Woutt)
{
    __shared__ ushort Ts[64][65];
    const int bid = blockIdx.x;

    if (bid < 512) {
        const int n4 = (B_ * T_ * D_) / 4;
        for (int i = bid * 256 + threadIdx.x; i < n4; i += 512 * 256) {
            float4 v = ((const float4*)x)[i];
            ushort4 o = { f2bf(v.x), f2bf(v.y), f2bf(v.z), f2bf(v.w) };
            ((ushort4*)xb)[i] = o;
        }
        return;
    }

    const float* W; ushort* Wt; int K, M, m0, k0;
    if (bid < 1280) {
        const int t = bid - 512;           // 48 x 16 tiles
        W = Wqkv; Wt = Wqkvt; K = D_; M = 3 * D_;
        m0 = (t % 48) * 64; k0 = (t / 48) * 64;
    } else {
        const int t = bid - 1280;          // 16 x 16 tiles
        W = Wout; Wt = Woutt; K = D_; M = D_;
        m0 = (t % 16) * 64; k0 = (t / 16) * 64;
    }

    const int tr = threadIdx.x >> 4;
    const int tc = threadIdx.x & 15;
    #pragma unroll
    for (int it = 0; it < 4; it++) {
        int k = tr + it * 16;
        float4 v = *(const float4*)&W[(size_t)(k0 + k) * M + m0 + tc * 4];
        Ts[tc * 4 + 0][k] = f2bf(v.x);
        Ts[tc * 4 + 1][k] = f2bf(v.y);
        Ts[tc * 4 + 2][k] = f2bf(v.z);
        Ts[tc * 4 + 3][k] = f2bf(v.w);
    }
    __syncthreads();
    #pragma unroll
    for (int it = 0; it < 2; it++) {
        const int mr  = (threadIdx.x >> 3) + it * 32;
        const int seg = (threadIdx.x & 7) * 8;
        short8 v;
        #pragma unroll
        for (int r = 0; r < 8; r++) v[r] = (short)Ts[mr][seg + r];
        *(short8*)&Wt[(size_t)(m0 + mr) * K + k0 + seg] = v;
    }
}

// ---------------------------------------------------------------------------
// QKV GEMM (round-6 proven 128x128 version): qkv = x @ WqkvT^T + b.
// 128x128 tile, BK=64, 4 waves (2x2), 4x4 MFMA/wave. Epilogue round-trips
// acc through the 32 KB staging LDS for coalesced stores: Q,K [b,h,t,d]
// (Q pre-scaled by 0.125*log2e), Vt [b,h,d,t].
// ---------------------------------------------------------------------------
__global__ __launch_bounds__(256, 4)
void gemm_qkv(const ushort* __restrict__ A, const ushort* __restrict__ Bt,
              const float* __restrict__ bias,
              ushort* __restrict__ Qg, ushort* __restrict__ Kg,
              ushort* __restrict__ Vtg)
{
    const int K = D_;
    __shared__ __align__(16) ushort lds[16384];   // staging, reused by epilogue
    ushort* Asl = lds;
    ushort* Bsl = lds + 8192;

    const int tid = threadIdx.x;
    const int w  = tid >> 6, L = tid & 63;
    const int lt = L & 15, lq = L >> 4;
    const int wr = w >> 1, wc = w & 1;
    const int m0 = blockIdx.x * 128, n0 = blockIdx.y * 128;
    const int rsub = L >> 3;
    const int pgr  = L & 7;

    f32x4 acc[4][4] = {};

    for (int k0 = 0; k0 < K; k0 += 64) {
        __syncthreads();
        #pragma unroll
        for (int j = 0; j < 4; j++) {
            const int row  = (w * 4 + j) * 8 + rsub;
            const int gran = pgr ^ rsub;
            load_lds_16B(A  + (size_t)(n0 + row) * K + k0 + gran * 8,
                         &Asl[row * 64 + pgr * 8]);
            load_lds_16B(Bt + (size_t)(m0 + row) * K + k0 + gran * 8,
                         &Bsl[row * 64 + pgr * 8]);
        }
        __syncthreads();

        #pragma unroll
        for (int ks = 0; ks < 2; ks++) {
            short8 af[4], bf[4];
            #pragma unroll
            for (int i = 0; i < 4; i++) {
                const int ra = wr * 64 + i * 16 + lt;
                af[i] = *(const short8*)&Asl[ra * 64 + (((ks * 4 + lq) ^ (ra & 7)) * 8)];
                const int rb = wc * 64 + i * 16 + lt;
                bf[i] = *(const short8*)&Bsl[rb * 64 + (((ks * 4 + lq) ^ (rb & 7)) * 8)];
            }
            #pragma unroll
            for (int i = 0; i < 4; i++)
                #pragma unroll
                for (int j = 0; j < 4; j++)
                    acc[i][j] = __builtin_amdgcn_mfma_f32_16x16x32_bf16(af[i], bf[j], acc[i][j], 0, 0, 0);
        }
    }

    __syncthreads();   // staging reads complete; reuse lds for epilogue
    const int s  = m0 >> 10;                       // block-uniform
    const int h0 = (m0 & 1023) >> 6;               // first of 2 heads
    const float qs = (s == 0) ? 0.18033688011112042f : 1.0f;   // 0.125*log2(e)

    if (s < 2) {
        // LDS[n][m] bf16 (stride 128); scalar writes are lane-consecutive in m
        #pragma unroll
        for (int j = 0; j < 4; j++) {
            const int m  = wc * 64 + j * 16 + lt;
            const float bv = bias[m0 + m];
            #pragma unroll
            for (int i = 0; i < 4; i++) {
                const int n = wr * 64 + i * 16 + lq * 4;
                #pragma unroll
                for (int r = 0; r < 4; r++)
                    lds[(n + r) * 128 + m] = f2bf((acc[i][j][r] + bv) * qs);
            }
        }
        __syncthreads();
        ushort* dst = (s == 0 ? Qg : Kg);
        #pragma unroll
        for (int it = 0; it < 8; it++) {
            const int g   = tid + it * 256;        // 0..2047
            const int row = g >> 4, c = g & 15;
            const int n = n0 + row;
            const int b = n >> 11, t = n & 2047;
            const int h = h0 + (c >> 3), d = (c & 7) * 8;
            short8 v = *(const short8*)&lds[row * 128 + c * 8];
            *(short8*)&dst[((size_t)(b * H_ + h) * T_ + t) * HD_ + d] = v;
        }
    } else {
        // LDS[m][n] bf16 (stride 128); packed b64 along n (r-consecutive)
        #pragma unroll
        for (int j = 0; j < 4; j++) {
            const int m  = wc * 64 + j * 16 + lt;
            const float bv = bias[m0 + m];
            #pragma unroll
            for (int i = 0; i < 4; i++) {
                const int n = wr * 64 + i * 16 + lq * 4;
                uint2 pk = { pack_bf2_fast(acc[i][j][0] + bv, acc[i][j][1] + bv),
                             pack_bf2_fast(acc[i][j][2] + bv, acc[i][j][3] + bv) };
                *(uint2*)&lds[m * 128 + n] = pk;
            }
        }
        __syncthreads();
        const int b = n0 >> 11, t0 = n0 & 2047;
        #pragma unroll
        for (int it = 0; it < 8; it++) {
            const int g   = tid + it * 256;
            const int row = g >> 4, c = g & 15;    // row = m, c = t-chunk
            const int h = h0 + (row >> 6), d = row & 63;
            short8 v = *(const short8*)&lds[row * 128 + c * 8];
            *(short8*)&Vtg[((size_t)(b * H_ + h) * HD_ + d) * T_ + t0 + c * 8] = v;
        }
    }
}

// ---------------------------------------------------------------------------
// Out GEMM: out = y @ WoutT^T + b. 128n x 64m tile, 512 blocks. MFMA operands
// SWAPPED (A-op = W m-rows, B-op = y n-rows) so D's reg quad = 4 consecutive
// m -> direct float4 stores, no LDS round trip.
// ---------------------------------------------------------------------------
__global__ __launch_bounds__(256, 4)
void gemm_out(const ushort* __restrict__ A, const ushort* __restrict__ Bt,
              const float* __restrict__ bias, float* __restrict__ C)
{
    const int K = D_, M = D_;
    __shared__ __align__(16) ushort lds[8192 + 4096];   // y 128x64 | W 64x64
    ushort* Asl = lds;
    ushort* Bsl = lds + 8192;

    const int tid = threadIdx.x;
    const int w  = tid >> 6, L = tid & 63;
    const int lt = L & 15, lq = L >> 4;
    const int wr = w >> 1, wc = w & 1;
    const int m0 = blockIdx.x * 64, n0 = blockIdx.y * 128;
    const int rsub = L >> 3;
    const int pgr  = L & 7;

    f32x4 acc[2][4] = {};   // [m-tile][n-tile]

    for (int k0 = 0; k0 < K; k0 += 64) {
        __syncthreads();
        #pragma unroll
        for (int j = 0; j < 4; j++) {
            const int row  = (w * 4 + j) * 8 + rsub;
            const int gran = pgr ^ rsub;
            load_lds_16B(A + (size_t)(n0 + row) * K + k0 + gran * 8,
                         &Asl[row * 64 + pgr * 8]);
        }
        #pragma unroll
        for (int j = 0; j < 2; j++) {
            const int row  = (w * 2 + j) * 8 + rsub;
            const int gran = pgr ^ rsub;
            load_lds_16B(Bt + (size_t)(m0 + row) * K + k0 + gran * 8,
                         &Bsl[row * 64 + pgr * 8]);
        }
        __syncthreads();

        #pragma unroll
        for (int ks = 0; ks < 2; ks++) {
            short8 wf[2], yf[4];
            #pragma unroll
            for (int j = 0; j < 2; j++) {
                const int rb = wc * 32 + j * 16 + lt;
                wf[j] = *(const short8*)&Bsl[rb * 64 + (((ks * 4 + lq) ^ (rb & 7)) * 8)];
            }
            #pragma unroll
            for (int i = 0; i < 4; i++) {
                const int ra = wr * 64 + i * 16 + lt;
                yf[i] = *(const short8*)&Asl[ra * 64 + (((ks * 4 + lq) ^ (ra & 7)) * 8)];
            }
            #pragma unroll
            for (int j = 0; j < 2; j++)
                #pragma unroll
                for (int i = 0; i < 4; i++)
                    acc[j][i] = __builtin_amdgcn_mfma_f32_16x16x32_bf16(wf[j], yf[i], acc[j][i], 0, 0, 0);
        }
    }

    // D layout: row (lq*4+r) = m within tile, col (lt) = n within tile
    #pragma unroll
    for (int j = 0; j < 2; j++) {
        const int mbase = m0 + wc * 32 + j * 16 + lq * 4;
        const float4 bv = *(const float4*)&bias[mbase];
        #pragma unroll
        for (int i = 0; i < 4; i++) {
            const int n = n0 + wr * 64 + i * 16 + lt;
            float4 o = { acc[j][i][0] + bv.x, acc[j][i][1] + bv.y,
                         acc[j][i][2] + bv.z, acc[j][i][3] + bv.w };
            *(float4*)&C[(size_t)n * M + mbase] = o;
        }
    }
}

// ---------------------------------------------------------------------------
// MFMA flash attention v12 = v9/v10 structure (64-q blocks, 4 waves x 16 q,
// 1024 blocks = 4 blocks/CU, 16 waves/CU, zero-shuffle PV via permuted
// K-row feed) with V-STAGING REMOVED (catalog Common-mistake #7 / m169):
// per (b,h) K+V = 512 KB, L2-resident, and the Vts staging swizzle exactly
// cancels at the read site (chunk (ks*4+lq)^kswz of row d holds global
// chunk ks*4+lq since d&7 == kswz) -- the LDS copy was a pure pass-through.
// V fragments now load straight from global (L2): per-lane staging loads
// halve (8->4), per-wave-tile ds_reads halve (32->16), LDS 32->16 KB, and
// V loads no longer depend on the staging barrier (issue ahead of it).
// (v11's 128-thread repack halved waves/CU -- reverted.)
// ---------------------------------------------------------------------------
__global__ __launch_bounds__(256, 4)
void attn_mfma(const ushort* __restrict__ Qg, const ushort* __restrict__ Kg,
               const ushort* __restrict__ Vtg, ushort* __restrict__ yb)
{
    const int h = blockIdx.y, b = blockIdx.z;
    const int flip = ((blockIdx.y >> 3) ^ blockIdx.z) & 1;
    const int qb = flip ? blockIdx.x : (31 - blockIdx.x);   // 32 q-blocks of 64
    const int tid = threadIdx.x;
    const int w  = tid >> 6, L = tid & 63;
    const int lt = L & 15, lq = L >> 4;
    const int kswz = lt & 7;

    __shared__ __align__(16) ushort Ks[128 * 64];   // 16 KB (K only)

    const size_t bh = (size_t)(b * H_ + h);
    const ushort* Qbase  = Qg  + bh * T_ * HD_;
    const ushort* Kbase  = Kg  + bh * T_ * HD_;
    const ushort* Vtbase = Vtg + bh * HD_ * T_;

    const int q_glob = qb * 64 + w * 16 + lt;
    const short8 qf0 = *(const short8*)(Qbase + (size_t)q_glob * HD_ + lq * 8);
    const short8 qf1 = *(const short8*)(Qbase + (size_t)q_glob * HD_ + 32 + lq * 8);

    f32x4 acc_o[4] = {};
    float lsum = 0.f;

    const int krow = tid >> 3, kpg = tid & 7;
    const int nk = (qb + 2) >> 1;

    // Permuted key rows for zero-shuffle PV: tile row p -> key (p>>2)*8+(p&3)
    const int prow = ((lt >> 2) * 8) + (lt & 3);

    // Per-lane V row bases (d = dt*16 + lt), read direct from global/L2.
    const ushort* Vr0 = Vtbase + (size_t)(0 * 16 + lt) * T_;
    const ushort* Vr1 = Vtbase + (size_t)(1 * 16 + lt) * T_;
    const ushort* Vr2 = Vtbase + (size_t)(2 * 16 + lt) * T_;
    const ushort* Vr3 = Vtbase + (size_t)(3 * 16 + lt) * T_;

    for (int kb = 0; kb < nk; kb++) {
        __syncthreads();
        // K staged with swzK(row) = ((row>>3)&1)*4 | (row&3); at the permuted
        // read rows this evaluates to lt&7 == kswz (same 8-way chunk spread).
        #pragma unroll
        for (int rr = 0; rr < 4; rr++) {
            const int row = krow + 32 * rr;
            const int swzK = (((row >> 3) & 1) * 4) | (row & 3);
            load_lds_16B(Kbase + (size_t)(kb * 128 + row) * HD_ + (kpg ^ swzK) * 8,
                         &Ks[row * 64 + kpg * 8]);
        }
        __syncthreads();

        const int tv = kb * 128 + lq * 8;   // V t-offset for this lane, ks=0

        if (kb < nk - 1) {
            // Branch-free fast path: all keys < every q of this block.
            #pragma unroll
            for (int ks = 0; ks < 4; ks++) {
                const int row0 = ks * 32 + prow;
                const int row1 = row0 + 4;
                short8 a00 = *(const short8*)&Ks[row0 * 64 + ((lq ^ kswz) * 8)];
                short8 a01 = *(const short8*)&Ks[row0 * 64 + (((4 + lq) ^ kswz) * 8)];
                short8 a10 = *(const short8*)&Ks[row1 * 64 + ((lq ^ kswz) * 8)];
                short8 a11 = *(const short8*)&Ks[row1 * 64 + (((4 + lq) ^ kswz) * 8)];
                f32x4 c0 = {}, c1 = {};
                c0 = __builtin_amdgcn_mfma_f32_16x16x32_bf16(a00, qf0, c0, 0, 0, 0);
                c0 = __builtin_amdgcn_mfma_f32_16x16x32_bf16(a01, qf1, c0, 0, 0, 0);
                c1 = __builtin_amdgcn_mfma_f32_16x16x32_bf16(a10, qf0, c1, 0, 0, 0);
                c1 = __builtin_amdgcn_mfma_f32_16x16x32_bf16(a11, qf1, c1, 0, 0, 0);

                // V fragments direct from global (L2-resident, no LDS dep)
                const int tvk = tv + ks * 32;
                short8 v0 = *(const short8*)(Vr0 + tvk);
                short8 v1 = *(const short8*)(Vr1 + tvk);
                short8 v2 = *(const short8*)(Vr2 + tvk);
                short8 v3 = *(const short8*)(Vr3 + tvk);

                float p[8];
                #pragma unroll
                for (int r = 0; r < 4; r++) { p[r] = EXP2F(c0[r]); p[4 + r] = EXP2F(c1[r]); }
                lsum += ((p[0] + p[1]) + (p[2] + p[3])) + ((p[4] + p[5]) + (p[6] + p[7]));

                uint32x4 pw = { pack_bf2_fast(p[0], p[1]), pack_bf2_fast(p[2], p[3]),
                                pack_bf2_fast(p[4], p[5]), pack_bf2_fast(p[6], p[7]) };
                short8 pf = __builtin_bit_cast(short8, pw);

                acc_o[0] = __builtin_amdgcn_mfma_f32_16x16x32_bf16(pf, v0, acc_o[0], 0, 0, 0);
                acc_o[1] = __builtin_amdgcn_mfma_f32_16x16x32_bf16(pf, v1, acc_o[1], 0, 0, 0);
                acc_o[2] = __builtin_amdgcn_mfma_f32_16x16x32_bf16(pf, v2, acc_o[2], 0, 0, 0);
                acc_o[3] = __builtin_amdgcn_mfma_f32_16x16x32_bf16(pf, v3, acc_o[3], 0, 0, 0);
            }
        } else {
            // Last tile: masked, runtime trip count (qb even: 2 ks, all
            // masked; qb odd: 4 ks, last 2 masked).
            const int ksN = (qb & 1) ? 4 : 2;
            const int mk0 = (qb & 1) ? 2 : 0;
            for (int ks = 0; ks < ksN; ks++) {
                const int row0 = ks * 32 + prow;
                const int row1 = row0 + 4;
                short8 a00 = *(const short8*)&Ks[row0 * 64 + ((lq ^ kswz) * 8)];
                short8 a01 = *(const short8*)&Ks[row0 * 64 + (((4 + lq) ^ kswz) * 8)];
                short8 a10 = *(const short8*)&Ks[row1 * 64 + ((lq ^ kswz) * 8)];
                short8 a11 = *(const short8*)&Ks[row1 * 64 + (((4 + lq) ^ kswz) * 8)];
                f32x4 c0 = {}, c1 = {};
                c0 = __builtin_amdgcn_mfma_f32_16x16x32_bf16(a00, qf0, c0, 0, 0, 0);
                c0 = __builtin_amdgcn_mfma_f32_16x16x32_bf16(a01, qf1, c0, 0, 0, 0);
                c1 = __builtin_amdgcn_mfma_f32_16x16x32_bf16(a10, qf0, c1, 0, 0, 0);
                c1 = __builtin_amdgcn_mfma_f32_16x16x32_bf16(a11, qf1, c1, 0, 0, 0);

                const int tvk = tv + ks * 32;
                short8 v0 = *(const short8*)(Vr0 + tvk);
                short8 v1 = *(const short8*)(Vr1 + tvk);
                short8 v2 = *(const short8*)(Vr2 + tvk);
                short8 v3 = *(const short8*)(Vr3 + tvk);

                float p[8];
                #pragma unroll
                for (int r = 0; r < 4; r++) { p[r] = EXP2F(c0[r]); p[4 + r] = EXP2F(c1[r]); }
                if (ks >= mk0) {
                    const int key0 = kb * 128 + ks * 32 + lq * 8;
                    #pragma unroll
                    for (int r = 0; r < 4; r++) {
                        if (key0 + r > q_glob)     p[r]     = 0.f;
                        if (key0 + 4 + r > q_glob) p[4 + r] = 0.f;
                    }
                }
                lsum += ((p[0] + p[1]) + (p[2] + p[3])) + ((p[4] + p[5]) + (p[6] + p[7]));

                uint32x4 pw = { pack_bf2_fast(p[0], p[1]), pack_bf2_fast(p[2], p[3]),
                                pack_bf2_fast(p[4], p[5]), pack_bf2_fast(p[6], p[7]) };
                short8 pf = __builtin_bit_cast(short8, pw);

                acc_o[0] = __builtin_amdgcn_mfma_f32_16x16x32_bf16(pf, v0, acc_o[0], 0, 0, 0);
                acc_o[1] = __builtin_amdgcn_mfma_f32_16x16x32_bf16(pf, v1, acc_o[1], 0, 0, 0);
                acc_o[2] = __builtin_amdgcn_mfma_f32_16x16x32_bf16(pf, v2, acc_o[2], 0, 0, 0);
                acc_o[3] = __builtin_amdgcn_mfma_f32_16x16x32_bf16(pf, v3, acc_o[3], 0, 0, 0);
            }
        }
    }

    lsum += __shfl_xor(lsum, 16, 64);
    lsum += __shfl_xor(lsum, 32, 64);
    const float inv = 1.0f / lsum;

    float linv[4];
    #pragma unroll
    for (int r = 0; r < 4; r++) linv[r] = __shfl(inv, lq * 4 + r, 64);

    ushort* ybase = yb + (size_t)(b * T_ + qb * 64 + w * 16) * D_ + h * HD_;
    #pragma unroll
    for (int r = 0; r < 4; r++)
        #pragma unroll
        for (int dt = 0; dt < 4; dt++)
            ybase[(size_t)(lq * 4 + r) * D_ + dt * 16 + lt] = f2bf(acc_o[dt][r] * linv[r]);
}

// ---------------------------------------------------------------------------
extern "C" void kernel_launch(void* const* d_in, const int* in_sizes, int n_in,
                              void* d_out, int out_size, void* d_ws, size_t ws_size,
                              hipStream_t stream)
{
    const float* x    = (const float*)d_in[0];
    const float* Wqkv = (const float*)d_in[1];
    const float* bqkv = (const float*)d_in[2];
    const float* Wout = (const float*)d_in[3];
    const float* bout = (const float*)d_in[4];
    float* out = (float*)d_out;

    char* ws = (char*)d_ws;
    const size_t NT = (size_t)B_ * T_;
    ushort* xb     = (ushort*)ws;
    ushort* Wqkvt  = (ushort*)(ws + NT * D_ * 2);
    ushort* Woutt  = (ushort*)(ws + NT * D_ * 2 + (size_t)3 * D_ * D_ * 2);
    char*   p      = ws + NT * D_ * 2 + (size_t)4 * D_ * D_ * 2;
    const size_t qkv_elems = (size_t)B_ * H_ * T_ * HD_;
    ushort* Qg  = (ushort*)p;
    ushort* Kg  = (ushort*)(p + qkv_elems * 2);
    ushort* Vtg = (ushort*)(p + qkv_elems * 4);
    ushort* yb  = (ushort*)(p + qkv_elems * 6);

    prep_kernel<<<1536, 256, 0, stream>>>(x, xb, Wqkv, Wqkvt, Wout, Woutt);

    gemm_qkv<<<dim3(3 * D_ / 128, NT / 128), 256, 0, stream>>>(
        xb, Wqkvt, bqkv, Qg, Kg, Vtg);

    attn_mfma<<<dim3(32, H_, B_), 256, 0, stream>>>(Qg, Kg, Vtg, yb);

    gemm_out<<<dim3(D_ / 64, NT / 128), 256, 0, stream>>>(
        yb, Woutt, bout, out);
}

// Round 10
// 173.568 us; speedup vs baseline: 1.1701x; 1.1701x over previous
//
#include <hip/hip_runtime.h>
#include <hip/hip_bf16.h>
#include <math.h>

#define B_  2
#define T_  2048
#define D_  1024
#define H_  16
#define HD_ 64

typedef __attribute__((ext_vector_type(8))) short short8;
typedef __attribute__((ext_vector_type(4))) float f32x4;
typedef __attribute__((ext_vector_type(4))) unsigned uint32x4;

#if __has_builtin(__builtin_amdgcn_exp2f)
#define EXP2F __builtin_amdgcn_exp2f
#else
#define EXP2F exp2f
#endif

__device__ __forceinline__ ushort f2bf(float x) {
    unsigned u = __builtin_bit_cast(unsigned, x);
    return (ushort)((u + 0x7FFFu + ((u >> 16) & 1u)) >> 16);  // RTNE
}

// round-half-up bf16 pair pack
__device__ __forceinline__ unsigned pack_bf2_fast(float a, float b) {
    unsigned ua = __builtin_bit_cast(unsigned, a) + 0x8000u;
    unsigned ub = __builtin_bit_cast(unsigned, b) + 0x8000u;
    return (ua >> 16) | (ub & 0xFFFF0000u);
}

__device__ __forceinline__ void load_lds_16B(const ushort* g, ushort* l) {
    __builtin_amdgcn_global_load_lds(
        (const __attribute__((address_space(1))) unsigned*)g,
        (__attribute__((address_space(3))) unsigned*)l, 16, 0, 0);
}

// ---------------------------------------------------------------------------
// Merged prep: [0,512) cast x->bf16; [512,1280) transpose Wqkv; [1280,1536)
// transpose Wout. Wt stores are 16B/lane (full-line coalesced).
// ---------------------------------------------------------------------------
__global__ __launch_bounds__(256)
void prep_kernel(const float* __restrict__ x, ushort* __restrict__ xb,
                 const float* __restrict__ Wqkv, ushort* __restrict__ Wqkvt,
                 const float* __restrict__ Wout, ushort* __restrict__ Woutt)
{
    __shared__ ushort Ts[64][65];
    const int bid = blockIdx.x;

    if (bid < 512) {
        const int n4 = (B_ * T_ * D_) / 4;
        for (int i = bid * 256 + threadIdx.x; i < n4; i += 512 * 256) {
            float4 v = ((const float4*)x)[i];
            ushort4 o = { f2bf(v.x), f2bf(v.y), f2bf(v.z), f2bf(v.w) };
            ((ushort4*)xb)[i] = o;
        }
        return;
    }

    const float* W; ushort* Wt; int K, M, m0, k0;
    if (bid < 1280) {
        const int t = bid - 512;           // 48 x 16 tiles
        W = Wqkv; Wt = Wqkvt; K = D_; M = 3 * D_;
        m0 = (t % 48) * 64; k0 = (t / 48) * 64;
    } else {
        const int t = bid - 1280;          // 16 x 16 tiles
        W = Wout; Wt = Woutt; K = D_; M = D_;
        m0 = (t % 16) * 64; k0 = (t / 16) * 64;
    }

    const int tr = threadIdx.x >> 4;
    const int tc = threadIdx.x & 15;
    #pragma unroll
    for (int it = 0; it < 4; it++) {
        int k = tr + it * 16;
        float4 v = *(const float4*)&W[(size_t)(k0 + k) * M + m0 + tc * 4];
        Ts[tc * 4 + 0][k] = f2bf(v.x);
        Ts[tc * 4 + 1][k] = f2bf(v.y);
        Ts[tc * 4 + 2][k] = f2bf(v.z);
        Ts[tc * 4 + 3][k] = f2bf(v.w);
    }
    __syncthreads();
    #pragma unroll
    for (int it = 0; it < 2; it++) {
        const int mr  = (threadIdx.x >> 3) + it * 32;
        const int seg = (threadIdx.x & 7) * 8;
        short8 v;
        #pragma unroll
        for (int r = 0; r < 8; r++) v[r] = (short)Ts[mr][seg + r];
        *(short8*)&Wt[(size_t)(m0 + mr) * K + k0 + seg] = v;
    }
}

// ---------------------------------------------------------------------------
// QKV GEMM (round-6 proven 128x128 version): qkv = x @ WqkvT^T + b.
// 128x128 tile, BK=64, 4 waves (2x2), 4x4 MFMA/wave. Epilogue round-trips
// acc through the 32 KB staging LDS for coalesced stores: Q,K [b,h,t,d]
// (Q pre-scaled by 0.125*log2e), Vt [b,h,d,t].
// ---------------------------------------------------------------------------
__global__ __launch_bounds__(256, 4)
void gemm_qkv(const ushort* __restrict__ A, const ushort* __restrict__ Bt,
              const float* __restrict__ bias,
              ushort* __restrict__ Qg, ushort* __restrict__ Kg,
              ushort* __restrict__ Vtg)
{
    const int K = D_;
    __shared__ __align__(16) ushort lds[16384];   // staging, reused by epilogue
    ushort* Asl = lds;
    ushort* Bsl = lds + 8192;

    const int tid = threadIdx.x;
    const int w  = tid >> 6, L = tid & 63;
    const int lt = L & 15, lq = L >> 4;
    const int wr = w >> 1, wc = w & 1;
    const int m0 = blockIdx.x * 128, n0 = blockIdx.y * 128;
    const int rsub = L >> 3;
    const int pgr  = L & 7;

    f32x4 acc[4][4] = {};

    for (int k0 = 0; k0 < K; k0 += 64) {
        __syncthreads();
        #pragma unroll
        for (int j = 0; j < 4; j++) {
            const int row  = (w * 4 + j) * 8 + rsub;
            const int gran = pgr ^ rsub;
            load_lds_16B(A  + (size_t)(n0 + row) * K + k0 + gran * 8,
                         &Asl[row * 64 + pgr * 8]);
            load_lds_16B(Bt + (size_t)(m0 + row) * K + k0 + gran * 8,
                         &Bsl[row * 64 + pgr * 8]);
        }
        __syncthreads();

        #pragma unroll
        for (int ks = 0; ks < 2; ks++) {
            short8 af[4], bf[4];
            #pragma unroll
            for (int i = 0; i < 4; i++) {
                const int ra = wr * 64 + i * 16 + lt;
                af[i] = *(const short8*)&Asl[ra * 64 + (((ks * 4 + lq) ^ (ra & 7)) * 8)];
                const int rb = wc * 64 + i * 16 + lt;
                bf[i] = *(const short8*)&Bsl[rb * 64 + (((ks * 4 + lq) ^ (rb & 7)) * 8)];
            }
            #pragma unroll
            for (int i = 0; i < 4; i++)
                #pragma unroll
                for (int j = 0; j < 4; j++)
                    acc[i][j] = __builtin_amdgcn_mfma_f32_16x16x32_bf16(af[i], bf[j], acc[i][j], 0, 0, 0);
        }
    }

    __syncthreads();   // staging reads complete; reuse lds for epilogue
    const int s  = m0 >> 10;                       // block-uniform
    const int h0 = (m0 & 1023) >> 6;               // first of 2 heads
    const float qs = (s == 0) ? 0.18033688011112042f : 1.0f;   // 0.125*log2(e)

    if (s < 2) {
        // LDS[n][m] bf16 (stride 128); scalar writes are lane-consecutive in m
        #pragma unroll
        for (int j = 0; j < 4; j++) {
            const int m  = wc * 64 + j * 16 + lt;
            const float bv = bias[m0 + m];
            #pragma unroll
            for (int i = 0; i < 4; i++) {
                const int n = wr * 64 + i * 16 + lq * 4;
                #pragma unroll
                for (int r = 0; r < 4; r++)
                    lds[(n + r) * 128 + m] = f2bf((acc[i][j][r] + bv) * qs);
            }
        }
        __syncthreads();
        ushort* dst = (s == 0 ? Qg : Kg);
        #pragma unroll
        for (int it = 0; it < 8; it++) {
            const int g   = tid + it * 256;        // 0..2047
            const int row = g >> 4, c = g & 15;
            const int n = n0 + row;
            const int b = n >> 11, t = n & 2047;
            const int h = h0 + (c >> 3), d = (c & 7) * 8;
            short8 v = *(const short8*)&lds[row * 128 + c * 8];
            *(short8*)&dst[((size_t)(b * H_ + h) * T_ + t) * HD_ + d] = v;
        }
    } else {
        // LDS[m][n] bf16 (stride 128); packed b64 along n (r-consecutive)
        #pragma unroll
        for (int j = 0; j < 4; j++) {
            const int m  = wc * 64 + j * 16 + lt;
            const float bv = bias[m0 + m];
            #pragma unroll
            for (int i = 0; i < 4; i++) {
                const int n = wr * 64 + i * 16 + lq * 4;
                uint2 pk = { pack_bf2_fast(acc[i][j][0] + bv, acc[i][j][1] + bv),
                             pack_bf2_fast(acc[i][j][2] + bv, acc[i][j][3] + bv) };
                *(uint2*)&lds[m * 128 + n] = pk;
            }
        }
        __syncthreads();
        const int b = n0 >> 11, t0 = n0 & 2047;
        #pragma unroll
        for (int it = 0; it < 8; it++) {
            const int g   = tid + it * 256;
            const int row = g >> 4, c = g & 15;    // row = m, c = t-chunk
            const int h = h0 + (row >> 6), d = row & 63;
            short8 v = *(const short8*)&lds[row * 128 + c * 8];
            *(short8*)&Vtg[((size_t)(b * H_ + h) * HD_ + d) * T_ + t0 + c * 8] = v;
        }
    }
}

// ---------------------------------------------------------------------------
// Out GEMM: out = y @ WoutT^T + b. 128n x 64m tile, 512 blocks. MFMA operands
// SWAPPED (A-op = W m-rows, B-op = y n-rows) so D's reg quad = 4 consecutive
// m -> direct float4 stores, no LDS round trip.
// ---------------------------------------------------------------------------
__global__ __launch_bounds__(256, 4)
void gemm_out(const ushort* __restrict__ A, const ushort* __restrict__ Bt,
              const float* __restrict__ bias, float* __restrict__ C)
{
    const int K = D_, M = D_;
    __shared__ __align__(16) ushort lds[8192 + 4096];   // y 128x64 | W 64x64
    ushort* Asl = lds;
    ushort* Bsl = lds + 8192;

    const int tid = threadIdx.x;
    const int w  = tid >> 6, L = tid & 63;
    const int lt = L & 15, lq = L >> 4;
    const int wr = w >> 1, wc = w & 1;
    const int m0 = blockIdx.x * 64, n0 = blockIdx.y * 128;
    const int rsub = L >> 3;
    const int pgr  = L & 7;

    f32x4 acc[2][4] = {};   // [m-tile][n-tile]

    for (int k0 = 0; k0 < K; k0 += 64) {
        __syncthreads();
        #pragma unroll
        for (int j = 0; j < 4; j++) {
            const int row  = (w * 4 + j) * 8 + rsub;
            const int gran = pgr ^ rsub;
            load_lds_16B(A + (size_t)(n0 + row) * K + k0 + gran * 8,
                         &Asl[row * 64 + pgr * 8]);
        }
        #pragma unroll
        for (int j = 0; j < 2; j++) {
            const int row  = (w * 2 + j) * 8 + rsub;
            const int gran = pgr ^ rsub;
            load_lds_16B(Bt + (size_t)(m0 + row) * K + k0 + gran * 8,
                         &Bsl[row * 64 + pgr * 8]);
        }
        __syncthreads();

        #pragma unroll
        for (int ks = 0; ks < 2; ks++) {
            short8 wf[2], yf[4];
            #pragma unroll
            for (int j = 0; j < 2; j++) {
                const int rb = wc * 32 + j * 16 + lt;
                wf[j] = *(const short8*)&Bsl[rb * 64 + (((ks * 4 + lq) ^ (rb & 7)) * 8)];
            }
            #pragma unroll
            for (int i = 0; i < 4; i++) {
                const int ra = wr * 64 + i * 16 + lt;
                yf[i] = *(const short8*)&Asl[ra * 64 + (((ks * 4 + lq) ^ (ra & 7)) * 8)];
            }
            #pragma unroll
            for (int j = 0; j < 2; j++)
                #pragma unroll
                for (int i = 0; i < 4; i++)
                    acc[j][i] = __builtin_amdgcn_mfma_f32_16x16x32_bf16(wf[j], yf[i], acc[j][i], 0, 0, 0);
        }
    }

    // D layout: row (lq*4+r) = m within tile, col (lt) = n within tile
    #pragma unroll
    for (int j = 0; j < 2; j++) {
        const int mbase = m0 + wc * 32 + j * 16 + lq * 4;
        const float4 bv = *(const float4*)&bias[mbase];
        #pragma unroll
        for (int i = 0; i < 4; i++) {
            const int n = n0 + wr * 64 + i * 16 + lt;
            float4 o = { acc[j][i][0] + bv.x, acc[j][i][1] + bv.y,
                         acc[j][i][2] + bv.z, acc[j][i][3] + bv.w };
            *(float4*)&C[(size_t)n * M + mbase] = o;
        }
    }
}

// ---------------------------------------------------------------------------
// MFMA flash attention v13 = v9 inner structure (64-q tiles, 4 waves x 16 q,
// K+V LDS staging, zero-shuffle PV via permuted K-row feed, two-branch
// causal masking) with UNIFORM-DURATION BLOCKS: each block processes two
// q-tiles serially, qb = x and qb = 31-x, so every block runs exactly
// nk(x)+nk(31-x) = 17 KV-tiles. Grid 512 = exactly 2 blocks/CU, all equal
// length -> steady 8 waves/CU for the whole kernel, vs v9's 1024 co-resident
// variable-length blocks whose short ones finished early (occupancy decayed
// to ~3.8/32 slots avg, fully exposing staging stalls in the tail).
// (v12's V-unstaging quadrupled V L2 traffic -- reverted.)
// ---------------------------------------------------------------------------
__global__ __launch_bounds__(256, 2)
void attn_mfma(const ushort* __restrict__ Qg, const ushort* __restrict__ Kg,
               const ushort* __restrict__ Vtg, ushort* __restrict__ yb)
{
    const int h = blockIdx.y, b = blockIdx.z;
    const int tid = threadIdx.x;
    const int w  = tid >> 6, L = tid & 63;
    const int lt = L & 15, lq = L >> 4;
    const int kswz = lt & 7;

    __shared__ __align__(16) ushort Ks [128 * 64];
    __shared__ __align__(16) ushort Vts[64 * 128];

    const size_t bh = (size_t)(b * H_ + h);
    const ushort* Qbase  = Qg  + bh * T_ * HD_;
    const ushort* Kbase  = Kg  + bh * T_ * HD_;
    const ushort* Vtbase = Vtg + bh * HD_ * T_;

    const int krow = tid >> 3, kpg = tid & 7;
    const int vrow = tid >> 4, vpg = tid & 15;
    // Permuted key rows for zero-shuffle PV: tile row p -> key (p>>2)*8+(p&3)
    const int prow = ((lt >> 2) * 8) + (lt & 3);

    auto process = [&](int qb) {
        const int q_glob = qb * 64 + w * 16 + lt;
        const short8 qf0 = *(const short8*)(Qbase + (size_t)q_glob * HD_ + lq * 8);
        const short8 qf1 = *(const short8*)(Qbase + (size_t)q_glob * HD_ + 32 + lq * 8);

        f32x4 acc_o[4] = {};
        float lsum = 0.f;
        const int nk = (qb + 2) >> 1;

        for (int kb = 0; kb < nk; kb++) {
            __syncthreads();
            // K staged with swzK(row) = ((row>>3)&1)*4 | (row&3); equals
            // lt&7 == kswz at the permuted read rows (8-way chunk spread).
            #pragma unroll
            for (int rr = 0; rr < 4; rr++) {
                const int row = krow + 32 * rr;
                const int swzK = (((row >> 3) & 1) * 4) | (row & 3);
                load_lds_16B(Kbase + (size_t)(kb * 128 + row) * HD_ + (kpg ^ swzK) * 8,
                             &Ks[row * 64 + kpg * 8]);
            }
            #pragma unroll
            for (int rr = 0; rr < 4; rr++) {
                const int d = vrow + 16 * rr;
                load_lds_16B(Vtbase + (size_t)d * T_ + kb * 128 + (vpg ^ (d & 7)) * 8,
                             &Vts[d * 128 + vpg * 8]);
            }
            __syncthreads();

            if (kb < nk - 1) {
                // Branch-free fast path: all keys < every q of this tile.
                #pragma unroll
                for (int ks = 0; ks < 4; ks++) {
                    const int row0 = ks * 32 + prow;
                    const int row1 = row0 + 4;
                    short8 a00 = *(const short8*)&Ks[row0 * 64 + ((lq ^ kswz) * 8)];
                    short8 a01 = *(const short8*)&Ks[row0 * 64 + (((4 + lq) ^ kswz) * 8)];
                    short8 a10 = *(const short8*)&Ks[row1 * 64 + ((lq ^ kswz) * 8)];
                    short8 a11 = *(const short8*)&Ks[row1 * 64 + (((4 + lq) ^ kswz) * 8)];
                    f32x4 c0 = {}, c1 = {};
                    c0 = __builtin_amdgcn_mfma_f32_16x16x32_bf16(a00, qf0, c0, 0, 0, 0);
                    c0 = __builtin_amdgcn_mfma_f32_16x16x32_bf16(a01, qf1, c0, 0, 0, 0);
                    c1 = __builtin_amdgcn_mfma_f32_16x16x32_bf16(a10, qf0, c1, 0, 0, 0);
                    c1 = __builtin_amdgcn_mfma_f32_16x16x32_bf16(a11, qf1, c1, 0, 0, 0);

                    float p[8];
                    #pragma unroll
                    for (int r = 0; r < 4; r++) { p[r] = EXP2F(c0[r]); p[4 + r] = EXP2F(c1[r]); }
                    lsum += ((p[0] + p[1]) + (p[2] + p[3])) + ((p[4] + p[5]) + (p[6] + p[7]));

                    uint32x4 pw = { pack_bf2_fast(p[0], p[1]), pack_bf2_fast(p[2], p[3]),
                                    pack_bf2_fast(p[4], p[5]), pack_bf2_fast(p[6], p[7]) };
                    short8 pf = __builtin_bit_cast(short8, pw);

                    #pragma unroll
                    for (int dt = 0; dt < 4; dt++) {
                        const int vr = dt * 16 + lt;
                        short8 vf = *(const short8*)&Vts[vr * 128 + (((ks * 4 + lq) ^ kswz) * 8)];
                        acc_o[dt] = __builtin_amdgcn_mfma_f32_16x16x32_bf16(pf, vf, acc_o[dt], 0, 0, 0);
                    }
                }
            } else {
                // Last tile: masked, runtime trip count (qb even: 2 ks, all
                // masked; qb odd: 4 ks, last 2 masked).
                const int ksN = (qb & 1) ? 4 : 2;
                const int mk0 = (qb & 1) ? 2 : 0;
                for (int ks = 0; ks < ksN; ks++) {
                    const int row0 = ks * 32 + prow;
                    const int row1 = row0 + 4;
                    short8 a00 = *(const short8*)&Ks[row0 * 64 + ((lq ^ kswz) * 8)];
                    short8 a01 = *(const short8*)&Ks[row0 * 64 + (((4 + lq) ^ kswz) * 8)];
                    short8 a10 = *(const short8*)&Ks[row1 * 64 + ((lq ^ kswz) * 8)];
                    short8 a11 = *(const short8*)&Ks[row1 * 64 + (((4 + lq) ^ kswz) * 8)];
                    f32x4 c0 = {}, c1 = {};
                    c0 = __builtin_amdgcn_mfma_f32_16x16x32_bf16(a00, qf0, c0, 0, 0, 0);
                    c0 = __builtin_amdgcn_mfma_f32_16x16x32_bf16(a01, qf1, c0, 0, 0, 0);
                    c1 = __builtin_amdgcn_mfma_f32_16x16x32_bf16(a10, qf0, c1, 0, 0, 0);
                    c1 = __builtin_amdgcn_mfma_f32_16x16x32_bf16(a11, qf1, c1, 0, 0, 0);

                    float p[8];
                    #pragma unroll
                    for (int r = 0; r < 4; r++) { p[r] = EXP2F(c0[r]); p[4 + r] = EXP2F(c1[r]); }
                    if (ks >= mk0) {
                        const int key0 = kb * 128 + ks * 32 + lq * 8;
                        #pragma unroll
                        for (int r = 0; r < 4; r++) {
                            if (key0 + r > q_glob)     p[r]     = 0.f;
                            if (key0 + 4 + r > q_glob) p[4 + r] = 0.f;
                        }
                    }
                    lsum += ((p[0] + p[1]) + (p[2] + p[3])) + ((p[4] + p[5]) + (p[6] + p[7]));

                    uint32x4 pw = { pack_bf2_fast(p[0], p[1]), pack_bf2_fast(p[2], p[3]),
                                    pack_bf2_fast(p[4], p[5]), pack_bf2_fast(p[6], p[7]) };
                    short8 pf = __builtin_bit_cast(short8, pw);

                    #pragma unroll
                    for (int dt = 0; dt < 4; dt++) {
                        const int vr = dt * 16 + lt;
                        short8 vf = *(const short8*)&Vts[vr * 128 + (((ks * 4 + lq) ^ kswz) * 8)];
                        acc_o[dt] = __builtin_amdgcn_mfma_f32_16x16x32_bf16(pf, vf, acc_o[dt], 0, 0, 0);
                    }
                }
            }
        }

        float ls = lsum;
        ls += __shfl_xor(ls, 16, 64);
        ls += __shfl_xor(ls, 32, 64);
        const float inv = 1.0f / ls;

        float linv[4];
        #pragma unroll
        for (int r = 0; r < 4; r++) linv[r] = __shfl(inv, lq * 4 + r, 64);

        ushort* ybase = yb + (size_t)(b * T_ + qb * 64 + w * 16) * D_ + h * HD_;
        #pragma unroll
        for (int r = 0; r < 4; r++)
            #pragma unroll
            for (int dt = 0; dt < 4; dt++)
                ybase[(size_t)(lq * 4 + r) * D_ + dt * 16 + lt] = f2bf(acc_o[dt][r] * linv[r]);
    };

    process(blockIdx.x);          // short q-tile  (nk = x/2 + 1)
    process(31 - blockIdx.x);     // long q-tile   (sum = 17 for all blocks)
}

// ---------------------------------------------------------------------------
extern "C" void kernel_launch(void* const* d_in, const int* in_sizes, int n_in,
                              void* d_out, int out_size, void* d_ws, size_t ws_size,
                              hipStream_t stream)
{
    const float* x    = (const float*)d_in[0];
    const float* Wqkv = (const float*)d_in[1];
    const float* bqkv = (const float*)d_in[2];
    const float* Wout = (const float*)d_in[3];
    const float* bout = (const float*)d_in[4];
    float* out = (float*)d_out;

    char* ws = (char*)d_ws;
    const size_t NT = (size_t)B_ * T_;
    ushort* xb     = (ushort*)ws;
    ushort* Wqkvt  = (ushort*)(ws + NT * D_ * 2);
    ushort* Woutt  = (ushort*)(ws + NT * D_ * 2 + (size_t)3 * D_ * D_ * 2);
    char*   p      = ws + NT * D_ * 2 + (size_t)4 * D_ * D_ * 2;
    const size_t qkv_elems = (size_t)B_ * H_ * T_ * HD_;
    ushort* Qg  = (ushort*)p;
    ushort* Kg  = (ushort*)(p + qkv_elems * 2);
    ushort* Vtg = (ushort*)(p + qkv_elems * 4);
    ushort* yb  = (ushort*)(p + qkv_elems * 6);

    prep_kernel<<<1536, 256, 0, stream>>>(x, xb, Wqkv, Wqkvt, Wout, Woutt);

    gemm_qkv<<<dim3(3 * D_ / 128, NT / 128), 256, 0, stream>>>(
        xb, Wqkvt, bqkv, Qg, Kg, Vtg);

    attn_mfma<<<dim3(16, H_, B_), 256, 0, stream>>>(Qg, Kg, Vtg, yb);

    gemm_out<<<dim3(D_ / 64, NT / 128), 256, 0, stream>>>(
        yb, Woutt, bout, out);
}

// Round 11
// 165.914 us; speedup vs baseline: 1.2241x; 1.0461x over previous
//
#include <hip/hip_runtime.h>
#include <hip/hip_bf16.h>
#include <math.h>

#define B_  2
#define T_  2048
#define D_  1024
#define H_  16
#define HD_ 64

typedef __attribute__((ext_vector_type(8))) short short8;
typedef __attribute__((ext_vector_type(4))) float f32x4;
typedef __attribute__((ext_vector_type(4))) unsigned uint32x4;

#if __has_builtin(__builtin_amdgcn_exp2f)
#define EXP2F __builtin_amdgcn_exp2f
#else
#define EXP2F exp2f
#endif

__device__ __forceinline__ ushort f2bf(float x) {
    unsigned u = __builtin_bit_cast(unsigned, x);
    return (ushort)((u + 0x7FFFu + ((u >> 16) & 1u)) >> 16);  // RTNE
}

// round-half-up bf16 pair pack
__device__ __forceinline__ unsigned pack_bf2_fast(float a, float b) {
    unsigned ua = __builtin_bit_cast(unsigned, a) + 0x8000u;
    unsigned ub = __builtin_bit_cast(unsigned, b) + 0x8000u;
    return (ua >> 16) | (ub & 0xFFFF0000u);
}

__device__ __forceinline__ void load_lds_16B(const ushort* g, ushort* l) {
    __builtin_amdgcn_global_load_lds(
        (const __attribute__((address_space(1))) unsigned*)g,
        (__attribute__((address_space(3))) unsigned*)l, 16, 0, 0);
}

// ---------------------------------------------------------------------------
// Merged prep: [0,512) cast x->bf16; [512,1280) transpose Wqkv; [1280,1536)
// transpose Wout. Wt stores are 16B/lane (full-line coalesced).
// ---------------------------------------------------------------------------
__global__ __launch_bounds__(256)
void prep_kernel(const float* __restrict__ x, ushort* __restrict__ xb,
                 const float* __restrict__ Wqkv, ushort* __restrict__ Wqkvt,
                 const float* __restrict__ Wout, ushort* __restrict__ Woutt)
{
    __shared__ ushort Ts[64][65];
    const int bid = blockIdx.x;

    if (bid < 512) {
        const int n4 = (B_ * T_ * D_) / 4;
        for (int i = bid * 256 + threadIdx.x; i < n4; i += 512 * 256) {
            float4 v = ((const float4*)x)[i];
            ushort4 o = { f2bf(v.x), f2bf(v.y), f2bf(v.z), f2bf(v.w) };
            ((ushort4*)xb)[i] = o;
        }
        return;
    }

    const float* W; ushort* Wt; int K, M, m0, k0;
    if (bid < 1280) {
        const int t = bid - 512;           // 48 x 16 tiles
        W = Wqkv; Wt = Wqkvt; K = D_; M = 3 * D_;
        m0 = (t % 48) * 64; k0 = (t / 48) * 64;
    } else {
        const int t = bid - 1280;          // 16 x 16 tiles
        W = Wout; Wt = Woutt; K = D_; M = D_;
        m0 = (t % 16) * 64; k0 = (t / 16) * 64;
    }

    const int tr = threadIdx.x >> 4;
    const int tc = threadIdx.x & 15;
    #pragma unroll
    for (int it = 0; it < 4; it++) {
        int k = tr + it * 16;
        float4 v = *(const float4*)&W[(size_t)(k0 + k) * M + m0 + tc * 4];
        Ts[tc * 4 + 0][k] = f2bf(v.x);
        Ts[tc * 4 + 1][k] = f2bf(v.y);
        Ts[tc * 4 + 2][k] = f2bf(v.z);
        Ts[tc * 4 + 3][k] = f2bf(v.w);
    }
    __syncthreads();
    #pragma unroll
    for (int it = 0; it < 2; it++) {
        const int mr  = (threadIdx.x >> 3) + it * 32;
        const int seg = (threadIdx.x & 7) * 8;
        short8 v;
        #pragma unroll
        for (int r = 0; r < 8; r++) v[r] = (short)Ts[mr][seg + r];
        *(short8*)&Wt[(size_t)(m0 + mr) * K + k0 + seg] = v;
    }
}

// ---------------------------------------------------------------------------
// QKV GEMM: qkv = x @ WqkvT^T + b. 128x128 tile, BK=64, 4 waves (2x2),
// 4x4 16x16x32 MFMA per wave. Epilogue round-trips acc through the 32 KB
// staging LDS to emit fully-coalesced 16B/lane stores: Q,K [b,h,t,d]
// (Q pre-scaled by 0.125*log2e), Vt [b,h,d,t].
// ---------------------------------------------------------------------------
__global__ __launch_bounds__(256, 4)
void gemm_qkv(const ushort* __restrict__ A, const ushort* __restrict__ Bt,
              const float* __restrict__ bias,
              ushort* __restrict__ Qg, ushort* __restrict__ Kg,
              ushort* __restrict__ Vtg)
{
    const int K = D_;
    __shared__ __align__(16) ushort lds[16384];   // staging, reused by epilogue
    ushort* Asl = lds;
    ushort* Bsl = lds + 8192;

    const int tid = threadIdx.x;
    const int w  = tid >> 6, L = tid & 63;
    const int lt = L & 15, lq = L >> 4;
    const int wr = w >> 1, wc = w & 1;
    const int m0 = blockIdx.x * 128, n0 = blockIdx.y * 128;
    const int rsub = L >> 3;
    const int pgr  = L & 7;

    f32x4 acc[4][4] = {};

    for (int k0 = 0; k0 < K; k0 += 64) {
        __syncthreads();
        #pragma unroll
        for (int j = 0; j < 4; j++) {
            const int row  = (w * 4 + j) * 8 + rsub;
            const int gran = pgr ^ rsub;
            load_lds_16B(A  + (size_t)(n0 + row) * K + k0 + gran * 8,
                         &Asl[row * 64 + pgr * 8]);
            load_lds_16B(Bt + (size_t)(m0 + row) * K + k0 + gran * 8,
                         &Bsl[row * 64 + pgr * 8]);
        }
        __syncthreads();

        #pragma unroll
        for (int ks = 0; ks < 2; ks++) {
            short8 af[4], bf[4];
            #pragma unroll
            for (int i = 0; i < 4; i++) {
                const int ra = wr * 64 + i * 16 + lt;
                af[i] = *(const short8*)&Asl[ra * 64 + (((ks * 4 + lq) ^ (ra & 7)) * 8)];
                const int rb = wc * 64 + i * 16 + lt;
                bf[i] = *(const short8*)&Bsl[rb * 64 + (((ks * 4 + lq) ^ (rb & 7)) * 8)];
            }
            #pragma unroll
            for (int i = 0; i < 4; i++)
                #pragma unroll
                for (int j = 0; j < 4; j++)
                    acc[i][j] = __builtin_amdgcn_mfma_f32_16x16x32_bf16(af[i], bf[j], acc[i][j], 0, 0, 0);
        }
    }

    __syncthreads();   // staging reads complete; reuse lds for epilogue
    const int s  = m0 >> 10;                       // block-uniform
    const int h0 = (m0 & 1023) >> 6;               // first of 2 heads
    const float qs = (s == 0) ? 0.18033688011112042f : 1.0f;   // 0.125*log2(e)

    if (s < 2) {
        // LDS[n][m] bf16 (stride 128); scalar writes are lane-consecutive in m
        #pragma unroll
        for (int j = 0; j < 4; j++) {
            const int m  = wc * 64 + j * 16 + lt;
            const float bv = bias[m0 + m];
            #pragma unroll
            for (int i = 0; i < 4; i++) {
                const int n = wr * 64 + i * 16 + lq * 4;
                #pragma unroll
                for (int r = 0; r < 4; r++)
                    lds[(n + r) * 128 + m] = f2bf((acc[i][j][r] + bv) * qs);
            }
        }
        __syncthreads();
        ushort* dst = (s == 0 ? Qg : Kg);
        #pragma unroll
        for (int it = 0; it < 8; it++) {
            const int g   = tid + it * 256;        // 0..2047
            const int row = g >> 4, c = g & 15;
            const int n = n0 + row;
            const int b = n >> 11, t = n & 2047;
            const int h = h0 + (c >> 3), d = (c & 7) * 8;
            short8 v = *(const short8*)&lds[row * 128 + c * 8];
            *(short8*)&dst[((size_t)(b * H_ + h) * T_ + t) * HD_ + d] = v;
        }
    } else {
        // LDS[m][n] bf16 (stride 128); packed b64 along n (r-consecutive)
        #pragma unroll
        for (int j = 0; j < 4; j++) {
            const int m  = wc * 64 + j * 16 + lt;
            const float bv = bias[m0 + m];
            #pragma unroll
            for (int i = 0; i < 4; i++) {
                const int n = wr * 64 + i * 16 + lq * 4;
                uint2 pk = { pack_bf2_fast(acc[i][j][0] + bv, acc[i][j][1] + bv),
                             pack_bf2_fast(acc[i][j][2] + bv, acc[i][j][3] + bv) };
                *(uint2*)&lds[m * 128 + n] = pk;
            }
        }
        __syncthreads();
        const int b = n0 >> 11, t0 = n0 & 2047;
        #pragma unroll
        for (int it = 0; it < 8; it++) {
            const int g   = tid + it * 256;
            const int row = g >> 4, c = g & 15;    // row = m, c = t-chunk
            const int h = h0 + (row >> 6), d = row & 63;
            short8 v = *(const short8*)&lds[row * 128 + c * 8];
            *(short8*)&Vtg[((size_t)(b * H_ + h) * HD_ + d) * T_ + t0 + c * 8] = v;
        }
    }
}

// ---------------------------------------------------------------------------
// Out GEMM: out = y @ WoutT^T + b. 128n x 64m tile, 512 blocks. MFMA operands
// SWAPPED (A-op = W m-rows, B-op = y n-rows) so D's reg quad = 4 consecutive
// m -> direct float4 stores, no LDS round trip.
// ---------------------------------------------------------------------------
__global__ __launch_bounds__(256, 4)
void gemm_out(const ushort* __restrict__ A, const ushort* __restrict__ Bt,
              const float* __restrict__ bias, float* __restrict__ C)
{
    const int K = D_, M = D_;
    __shared__ __align__(16) ushort lds[8192 + 4096];   // y 128x64 | W 64x64
    ushort* Asl = lds;
    ushort* Bsl = lds + 8192;

    const int tid = threadIdx.x;
    const int w  = tid >> 6, L = tid & 63;
    const int lt = L & 15, lq = L >> 4;
    const int wr = w >> 1, wc = w & 1;
    const int m0 = blockIdx.x * 64, n0 = blockIdx.y * 128;
    const int rsub = L >> 3;
    const int pgr  = L & 7;

    f32x4 acc[2][4] = {};   // [m-tile][n-tile]

    for (int k0 = 0; k0 < K; k0 += 64) {
        __syncthreads();
        #pragma unroll
        for (int j = 0; j < 4; j++) {
            const int row  = (w * 4 + j) * 8 + rsub;
            const int gran = pgr ^ rsub;
            load_lds_16B(A + (size_t)(n0 + row) * K + k0 + gran * 8,
                         &Asl[row * 64 + pgr * 8]);
        }
        #pragma unroll
        for (int j = 0; j < 2; j++) {
            const int row  = (w * 2 + j) * 8 + rsub;
            const int gran = pgr ^ rsub;
            load_lds_16B(Bt + (size_t)(m0 + row) * K + k0 + gran * 8,
                         &Bsl[row * 64 + pgr * 8]);
        }
        __syncthreads();

        #pragma unroll
        for (int ks = 0; ks < 2; ks++) {
            short8 wf[2], yf[4];
            #pragma unroll
            for (int j = 0; j < 2; j++) {
                const int rb = wc * 32 + j * 16 + lt;
                wf[j] = *(const short8*)&Bsl[rb * 64 + (((ks * 4 + lq) ^ (rb & 7)) * 8)];
            }
            #pragma unroll
            for (int i = 0; i < 4; i++) {
                const int ra = wr * 64 + i * 16 + lt;
                yf[i] = *(const short8*)&Asl[ra * 64 + (((ks * 4 + lq) ^ (ra & 7)) * 8)];
            }
            #pragma unroll
            for (int j = 0; j < 2; j++)
                #pragma unroll
                for (int i = 0; i < 4; i++)
                    acc[j][i] = __builtin_amdgcn_mfma_f32_16x16x32_bf16(wf[j], yf[i], acc[j][i], 0, 0, 0);
        }
    }

    // D layout: row (lq*4+r) = m within tile, col (lt) = n within tile
    #pragma unroll
    for (int j = 0; j < 2; j++) {
        const int mbase = m0 + wc * 32 + j * 16 + lq * 4;
        const float4 bv = *(const float4*)&bias[mbase];
        #pragma unroll
        for (int i = 0; i < 4; i++) {
            const int n = n0 + wr * 64 + i * 16 + lt;
            float4 o = { acc[j][i][0] + bv.x, acc[j][i][1] + bv.y,
                         acc[j][i][2] + bv.z, acc[j][i][3] + bv.w };
            *(float4*)&C[(size_t)n * M + mbase] = o;
        }
    }
}

// ---------------------------------------------------------------------------
// MFMA flash attention v9 (round-5 best-verified state): 64-q blocks,
// 16 q/wave, 1024 blocks = 4 blocks/CU, zero-shuffle PV via permuted K-row
// feed (lane (lq,lt) holds P for keys lq*8..lq*8+7 in-register; no Ps LDS
// round trip), two-branch inner loop: non-final KV tiles run a branch-free
// fully-unrolled 4x ks fast path (no mask code), masked runtime-trip loop
// only for the last tile. Session optimum: 166.7 us total.
// ---------------------------------------------------------------------------
__global__ __launch_bounds__(256, 4)
void attn_mfma(const ushort* __restrict__ Qg, const ushort* __restrict__ Kg,
               const ushort* __restrict__ Vtg, ushort* __restrict__ yb)
{
    const int h = blockIdx.y, b = blockIdx.z;
    const int flip = ((blockIdx.y >> 3) ^ blockIdx.z) & 1;
    const int qb = flip ? blockIdx.x : (31 - blockIdx.x);   // 32 q-blocks of 64
    const int tid = threadIdx.x;
    const int w  = tid >> 6, L = tid & 63;
    const int lt = L & 15, lq = L >> 4;
    const int kswz = lt & 7;

    __shared__ __align__(16) ushort Ks [128 * 64];
    __shared__ __align__(16) ushort Vts[64 * 128];

    const size_t bh = (size_t)(b * H_ + h);
    const ushort* Qbase  = Qg  + bh * T_ * HD_;
    const ushort* Kbase  = Kg  + bh * T_ * HD_;
    const ushort* Vtbase = Vtg + bh * HD_ * T_;

    const int q_glob = qb * 64 + w * 16 + lt;
    const short8 qf0 = *(const short8*)(Qbase + (size_t)q_glob * HD_ + lq * 8);
    const short8 qf1 = *(const short8*)(Qbase + (size_t)q_glob * HD_ + 32 + lq * 8);

    f32x4 acc_o[4] = {};
    float lsum = 0.f;

    const int krow = tid >> 3, kpg = tid & 7;
    const int vrow = tid >> 4, vpg = tid & 15;
    const int nk = (qb + 2) >> 1;

    for (int kb = 0; kb < nk; kb++) {
        __syncthreads();
        // K staged with swzK(row) = ((row>>3)&1)*4 | (row&3); at the permuted
        // read rows this evaluates to lt&7 == kswz (same 8-way chunk spread).
        #pragma unroll
        for (int rr = 0; rr < 4; rr++) {
            const int row = krow + 32 * rr;
            const int swzK = (((row >> 3) & 1) * 4) | (row & 3);
            load_lds_16B(Kbase + (size_t)(kb * 128 + row) * HD_ + (kpg ^ swzK) * 8,
                         &Ks[row * 64 + kpg * 8]);
        }
        #pragma unroll
        for (int rr = 0; rr < 4; rr++) {
            const int d = vrow + 16 * rr;
            load_lds_16B(Vtbase + (size_t)d * T_ + kb * 128 + (vpg ^ (d & 7)) * 8,
                         &Vts[d * 128 + vpg * 8]);
        }
        __syncthreads();

        if (kb < nk - 1) {
            // Branch-free fast path: all keys < every q of this block.
            #pragma unroll
            for (int ks = 0; ks < 4; ks++) {
                // Permuted key rows: tile row p -> key (p>>2)*8 + (p&3) (c0),
                // +4 (c1) => lane (lq,lt) holds keys lq*8..lq*8+7 in-register.
                const int row0 = ks * 32 + ((lt >> 2) * 8) + (lt & 3);
                const int row1 = row0 + 4;
                short8 a00 = *(const short8*)&Ks[row0 * 64 + ((lq ^ kswz) * 8)];
                short8 a01 = *(const short8*)&Ks[row0 * 64 + (((4 + lq) ^ kswz) * 8)];
                short8 a10 = *(const short8*)&Ks[row1 * 64 + ((lq ^ kswz) * 8)];
                short8 a11 = *(const short8*)&Ks[row1 * 64 + (((4 + lq) ^ kswz) * 8)];
                f32x4 c0 = {}, c1 = {};
                __builtin_amdgcn_s_setprio(1);
                c0 = __builtin_amdgcn_mfma_f32_16x16x32_bf16(a00, qf0, c0, 0, 0, 0);
                c0 = __builtin_amdgcn_mfma_f32_16x16x32_bf16(a01, qf1, c0, 0, 0, 0);
                c1 = __builtin_amdgcn_mfma_f32_16x16x32_bf16(a10, qf0, c1, 0, 0, 0);
                c1 = __builtin_amdgcn_mfma_f32_16x16x32_bf16(a11, qf1, c1, 0, 0, 0);
                __builtin_amdgcn_s_setprio(0);

                float p[8];
                #pragma unroll
                for (int r = 0; r < 4; r++) { p[r] = EXP2F(c0[r]); p[4 + r] = EXP2F(c1[r]); }
                lsum += ((p[0] + p[1]) + (p[2] + p[3])) + ((p[4] + p[5]) + (p[6] + p[7]));

                uint32x4 pw = { pack_bf2_fast(p[0], p[1]), pack_bf2_fast(p[2], p[3]),
                                pack_bf2_fast(p[4], p[5]), pack_bf2_fast(p[6], p[7]) };
                short8 pf = __builtin_bit_cast(short8, pw);

                __builtin_amdgcn_s_setprio(1);
                #pragma unroll
                for (int dt = 0; dt < 4; dt++) {
                    const int vr = dt * 16 + lt;
                    short8 vf = *(const short8*)&Vts[vr * 128 + (((ks * 4 + lq) ^ kswz) * 8)];
                    acc_o[dt] = __builtin_amdgcn_mfma_f32_16x16x32_bf16(pf, vf, acc_o[dt], 0, 0, 0);
                }
                __builtin_amdgcn_s_setprio(0);
            }
        } else {
            // Last tile: masked, runtime trip count (qb even: 2 ks, all
            // masked; qb odd: 4 ks, last 2 masked).
            const int ksN = (qb & 1) ? 4 : 2;
            const int mk0 = (qb & 1) ? 2 : 0;
            for (int ks = 0; ks < ksN; ks++) {
                const int row0 = ks * 32 + ((lt >> 2) * 8) + (lt & 3);
                const int row1 = row0 + 4;
                short8 a00 = *(const short8*)&Ks[row0 * 64 + ((lq ^ kswz) * 8)];
                short8 a01 = *(const short8*)&Ks[row0 * 64 + (((4 + lq) ^ kswz) * 8)];
                short8 a10 = *(const short8*)&Ks[row1 * 64 + ((lq ^ kswz) * 8)];
                short8 a11 = *(const short8*)&Ks[row1 * 64 + (((4 + lq) ^ kswz) * 8)];
                f32x4 c0 = {}, c1 = {};
                __builtin_amdgcn_s_setprio(1);
                c0 = __builtin_amdgcn_mfma_f32_16x16x32_bf16(a00, qf0, c0, 0, 0, 0);
                c0 = __builtin_amdgcn_mfma_f32_16x16x32_bf16(a01, qf1, c0, 0, 0, 0);
                c1 = __builtin_amdgcn_mfma_f32_16x16x32_bf16(a10, qf0, c1, 0, 0, 0);
                c1 = __builtin_amdgcn_mfma_f32_16x16x32_bf16(a11, qf1, c1, 0, 0, 0);
                __builtin_amdgcn_s_setprio(0);

                float p[8];
                #pragma unroll
                for (int r = 0; r < 4; r++) { p[r] = EXP2F(c0[r]); p[4 + r] = EXP2F(c1[r]); }
                if (ks >= mk0) {
                    const int key0 = kb * 128 + ks * 32 + lq * 8;
                    #pragma unroll
                    for (int r = 0; r < 4; r++) {
                        if (key0 + r > q_glob)     p[r]     = 0.f;
                        if (key0 + 4 + r > q_glob) p[4 + r] = 0.f;
                    }
                }
                lsum += ((p[0] + p[1]) + (p[2] + p[3])) + ((p[4] + p[5]) + (p[6] + p[7]));

                uint32x4 pw = { pack_bf2_fast(p[0], p[1]), pack_bf2_fast(p[2], p[3]),
                                pack_bf2_fast(p[4], p[5]), pack_bf2_fast(p[6], p[7]) };
                short8 pf = __builtin_bit_cast(short8, pw);

                __builtin_amdgcn_s_setprio(1);
                #pragma unroll
                for (int dt = 0; dt < 4; dt++) {
                    const int vr = dt * 16 + lt;
                    short8 vf = *(const short8*)&Vts[vr * 128 + (((ks * 4 + lq) ^ kswz) * 8)];
                    acc_o[dt] = __builtin_amdgcn_mfma_f32_16x16x32_bf16(pf, vf, acc_o[dt], 0, 0, 0);
                }
                __builtin_amdgcn_s_setprio(0);
            }
        }
    }

    lsum += __shfl_xor(lsum, 16, 64);
    lsum += __shfl_xor(lsum, 32, 64);
    const float inv = 1.0f / lsum;

    float linv[4];
    #pragma unroll
    for (int r = 0; r < 4; r++) linv[r] = __shfl(inv, lq * 4 + r, 64);

    ushort* ybase = yb + (size_t)(b * T_ + qb * 64 + w * 16) * D_ + h * HD_;
    #pragma unroll
    for (int r = 0; r < 4; r++)
        #pragma unroll
        for (int dt = 0; dt < 4; dt++)
            ybase[(size_t)(lq * 4 + r) * D_ + dt * 16 + lt] = f2bf(acc_o[dt][r] * linv[r]);
}

// ---------------------------------------------------------------------------
extern "C" void kernel_launch(void* const* d_in, const int* in_sizes, int n_in,
                              void* d_out, int out_size, void* d_ws, size_t ws_size,
                              hipStream_t stream)
{
    const float* x    = (const float*)d_in[0];
    const float* Wqkv = (const float*)d_in[1];
    const float* bqkv = (const float*)d_in[2];
    const float* Wout = (const float*)d_in[3];
    const float* bout = (const float*)d_in[4];
    float* out = (float*)d_out;

    char* ws = (char*)d_ws;
    const size_t NT = (size_t)B_ * T_;
    ushort* xb     = (ushort*)ws;
    ushort* Wqkvt  = (ushort*)(ws + NT * D_ * 2);
    ushort* Woutt  = (ushort*)(ws + NT * D_ * 2 + (size_t)3 * D_ * D_ * 2);
    char*   p      = ws + NT * D_ * 2 + (size_t)4 * D_ * D_ * 2;
    const size_t qkv_elems = (size_t)B_ * H_ * T_ * HD_;
    ushort* Qg  = (ushort*)p;
    ushort* Kg  = (ushort*)(p + qkv_elems * 2);
    ushort* Vtg = (ushort*)(p + qkv_elems * 4);
    ushort* yb  = (ushort*)(p + qkv_elems * 6);

    prep_kernel<<<1536, 256, 0, stream>>>(x, xb, Wqkv, Wqkvt, Wout, Woutt);

    gemm_qkv<<<dim3(3 * D_ / 128, NT / 128), 256, 0, stream>>>(
        xb, Wqkvt, bqkv, Qg, Kg, Vtg);

    attn_mfma<<<dim3(32, H_, B_), 256, 0, stream>>>(Qg, Kg, Vtg, yb);

    gemm_out<<<dim3(D_ / 64, NT / 128), 256, 0, stream>>>(
        yb, Woutt, bout, out);
}